// Round 8
// baseline (263.658 us; speedup 1.0000x reference)
//
#include <hip/hip_runtime.h>
#include <math.h>

#define NP 16384
#define NR 8192

typedef __attribute__((ext_vector_type(8))) short short8;
typedef __attribute__((ext_vector_type(4))) float f32x4;

__device__ inline unsigned short f2b(float f) {
  unsigned int x = __float_as_uint(f);
  return (unsigned short)((x + 0x7FFFu + ((x >> 16) & 1u)) >> 16);  // RNE
}
__device__ inline float blo(unsigned int u) { return __uint_as_float(u << 16); }
__device__ inline float bhi(unsigned int u) { return __uint_as_float(u & 0xffff0000u); }

// ---------------- fused preprocessing: blocks 0..127 rgb transpose (+rxyz4 pack),
// 128..383 pcd transpose, 384..959 weight f32->bf16 conversion
__global__ __launch_bounds__(256) void k_pre(const float* __restrict__ rf,
                                             const float* __restrict__ rxyz,
                                             const float* __restrict__ pf,
                                             const float* __restrict__ s0, const float* __restrict__ s1,
                                             const float* __restrict__ s2, const float* __restrict__ s3,
                                             const float* __restrict__ s4, const float* __restrict__ s5,
                                             const float* __restrict__ s6, const float* __restrict__ s7,
                                             unsigned short* __restrict__ rgbTb,
                                             float4* __restrict__ rxyz4,
                                             unsigned short* __restrict__ full,
                                             unsigned short* __restrict__ dst) {
  __shared__ float tile[128][65];
  int b = blockIdx.x, t = threadIdx.x;
  if (b < 128) {
    int r0 = b * 64;
    for (int e = 0; e < 32; ++e) {
      int idx = t + e * 256;
      int c = idx >> 6, rl = idx & 63;
      tile[c][rl] = rf[c * NR + r0 + rl];
    }
    __syncthreads();
    for (int e = 0; e < 32; ++e) {
      int idx = t + e * 256;
      int rl = idx >> 7, c = idx & 127;
      rgbTb[(size_t)(r0 + rl) * 128 + c] = f2b(tile[c][rl]);
    }
    if (b == 0 && t < 128) rgbTb[(size_t)NR * 128 + t] = 0;
    if ((t >> 6) == 0) {
      int i = r0 + (t & 63);
      float x = rxyz[i * 3], y = rxyz[i * 3 + 1], z = rxyz[i * 3 + 2];
      rxyz4[i] = make_float4(x, y, z, fmaf(x, x, fmaf(y, y, z * z)));
    }
  } else if (b < 384) {
    int n0 = (b - 128) * 64;
    for (int e = 0; e < 8; ++e) {
      int idx = t + e * 256;
      int c = idx >> 6, nl = idx & 63;
      tile[c][nl] = pf[c * NP + n0 + nl];
    }
    __syncthreads();
    for (int e = 0; e < 8; ++e) {
      int idx = t + e * 256;
      int nl = idx >> 5, c = idx & 31;
      full[(size_t)(n0 + nl) * 160 + c] = f2b(tile[c][nl]);
    }
  } else {
    const int sizes[8] = {147456, 49152, 65536, 32768, 25600, 25600, 20480, 16384};
    const int offs[8]  = {0, 147456, 196608, 262144, 294912, 320512, 346112, 366592};
    const float* srcs[8] = {s0, s1, s2, s3, s4, s5, s6, s7};
    int j = b - 384;
    int m = j / 72, bx = j % 72;
    int i = (bx * 256 + t) * 8;
    if (i >= sizes[m]) return;
    const float4* sp = (const float4*)(srcs[m] + i);
    float4 a = sp[0], c = sp[1];
    uint4 o;
    o.x = f2b(a.x) | ((unsigned int)f2b(a.y) << 16);
    o.y = f2b(a.z) | ((unsigned int)f2b(a.w) << 16);
    o.z = f2b(c.x) | ((unsigned int)f2b(c.y) << 16);
    o.w = f2b(c.z) | ((unsigned int)f2b(c.w) << 16);
    *(uint4*)(dst + offs[m] + i) = o;
  }
}

// ---------------- three_nn partials (unchanged, R6-verified)
__global__ __launch_bounds__(256) void k_nn_part(const float* __restrict__ pxyz,
                                                 const float4* __restrict__ rxyz4,
                                                 float* __restrict__ pd,
                                                 int* __restrict__ pi) {
  __shared__ float4 pts[1024];
  __shared__ float msd[4][3][64];
  __shared__ int   mid[4][3][64];
  int t = threadIdx.x;
  int g = blockIdx.x, s = blockIdx.y;
  int lane = t & 63, w = t >> 6;
  int rbase = s * 1024;
#pragma unroll
  for (int e = 0; e < 4; ++e) {
    int q = t + e * 256;
    pts[q] = rxyz4[rbase + q];
  }
  int n = g * 64 + lane;
  float px = pxyz[n * 3], py = pxyz[n * 3 + 1], pz = pxyz[n * 3 + 2];
  float pp = fmaf(px, px, fmaf(py, py, pz * pz));
  float nx2 = -2.f * px, ny2 = -2.f * py, nz2 = -2.f * pz;
  __syncthreads();
  const float R2L = 0.005626125f;          // 0.075^2 * 1.0002 sentinel (> R2 -> masks to NR)
  const float MARGIN = 4e-6f;              // covers fp32 error of expanded form
  float s0 = R2L, s1 = R2L, s2 = R2L;
  int i0 = 0, i1 = 0, i2 = 0;
  float thr = R2L + MARGIN - pp;
  int base = w * 256;
#pragma unroll 8
  for (int loc = 0; loc < 256; ++loc) {
    float4 r = pts[base + loc];            // wave-uniform address -> LDS broadcast
    float e3 = fmaf(nz2, r.z, fmaf(ny2, r.y, fmaf(nx2, r.x, r.w)));
    if (__ballot(e3 < thr)) {              // wave-uniform branch
      float dx = px - r.x, dy = py - r.y, dz = pz - r.z;
      float d2 = fmaf(dx, dx, fmaf(dy, dy, dz * dz));
      if (d2 < s2) {                       // exact strict <: reference tie-break
        int i = rbase + base + loc;
        if (d2 < s1) {
          s2 = s1; i2 = i1;
          if (d2 < s0) { s1 = s0; i1 = i0; s0 = d2; i0 = i; }
          else         { s1 = d2; i1 = i; }
        } else { s2 = d2; i2 = i; }
      }
      thr = s2 + MARGIN - pp;
    }
  }
  msd[w][0][lane] = s0; msd[w][1][lane] = s1; msd[w][2][lane] = s2;
  mid[w][0][lane] = i0; mid[w][1][lane] = i1; mid[w][2][lane] = i2;
  __syncthreads();
  if (t < 64) {
    s0 = msd[0][0][t]; s1 = msd[0][1][t]; s2 = msd[0][2][t];
    i0 = mid[0][0][t]; i1 = mid[0][1][t]; i2 = mid[0][2][t];
    for (int ww = 1; ww < 4; ++ww) {       // ascending candidate order
      for (int q = 0; q < 3; ++q) {
        float d2 = msd[ww][q][t]; int i = mid[ww][q][t];
        if (d2 < s2) {
          if (d2 < s1) {
            s2 = s1; i2 = i1;
            if (d2 < s0) { s1 = s0; i1 = i0; s0 = d2; i0 = i; }
            else         { s1 = d2; i1 = i; }
          } else { s2 = d2; i2 = i; }
        }
      }
    }
    int off = ((g * 8 + s) * 64 + t) * 3;
    pd[off + 0] = s0; pd[off + 1] = s1; pd[off + 2] = s2;
    pi[off + 0] = i0; pi[off + 1] = i1; pi[off + 2] = i2;
  }
}

// ---------------- fused merge + gather + max (unchanged, R7-verified)
__global__ __launch_bounds__(256) void k_gather_max(const unsigned short* __restrict__ rgbTb,
                                                    const float* __restrict__ pd,
                                                    const int* __restrict__ pi,
                                                    unsigned short* __restrict__ xcat,
                                                    unsigned short* __restrict__ x2) {
  int t = threadIdx.x, lane = t & 63, w = t >> 6;
  int n = blockIdx.x * 4 + w;
  int g = n >> 6, l = n & 63;
  unsigned long long key = ~0ull;
  if (lane < 24) {
    int s = lane / 3, qq = lane % 3;
    int off = ((g * 8 + s) * 64 + l) * 3 + qq;
    key = ((unsigned long long)__float_as_uint(pd[off]) << 32) | (unsigned int)pi[off];
  }
  unsigned long long mk[3];
#pragma unroll
  for (int r = 0; r < 3; ++r) {
    unsigned long long m = key;
#pragma unroll
    for (int o = 1; o < 64; o <<= 1) {
      unsigned long long other = __shfl_xor(m, o);
      m = other < m ? other : m;
    }
    mk[r] = m;
    if (key == m) key = ~0ull;
  }
  const float R2 = 0.075f * 0.075f;
  float d0 = __uint_as_float((unsigned int)(mk[0] >> 32));
  float d1 = __uint_as_float((unsigned int)(mk[1] >> 32));
  float d2 = __uint_as_float((unsigned int)(mk[2] >> 32));
  int j0 = (d0 > R2) ? NR : (int)(mk[0] & 0xffffffffu);
  int j1 = (d1 > R2) ? NR : (int)(mk[1] & 0xffffffffu);
  int j2 = (d2 > R2) ? NR : (int)(mk[2] & 0xffffffffu);
  unsigned int a = ((const unsigned int*)(rgbTb + (size_t)j0 * 128))[lane];
  unsigned int b = ((const unsigned int*)(rgbTb + (size_t)j1 * 128))[lane];
  unsigned int c = ((const unsigned int*)(rgbTb + (size_t)j2 * 128))[lane];
  unsigned int* xr = (unsigned int*)(xcat + (size_t)n * 384);
  xr[lane] = a; xr[64 + lane] = b; xr[128 + lane] = c;
  float ml = fmaxf(blo(a), fmaxf(blo(b), blo(c)));
  float mh = fmaxf(bhi(a), fmaxf(bhi(b), bhi(c)));
  unsigned int m = (__float_as_uint(mh) & 0xffff0000u) | (__float_as_uint(ml) >> 16);
  ((unsigned int*)(x2 + (size_t)n * 256 + 128))[lane] = m;
}

// ---------------- bf16 MFMA GEMM (unchanged, front chain only)
template <bool BN, bool RELU>
__global__ __launch_bounds__(256) void k_bgemm(const unsigned short* __restrict__ Wb,
                                               const float* __restrict__ bias,
                                               const float* __restrict__ bnp,
                                               const unsigned short* __restrict__ X,
                                               unsigned short* __restrict__ Y,
                                               int O, int C, int ldY) {
  __shared__ unsigned short Xs[128 * 40];
  __shared__ unsigned short Wl[128 * 40];
  __shared__ float scsh[256];
  int t = threadIdx.x;
  int lane = t & 63, w = t >> 6;
  int wn = w & 1, wm = w >> 1;
  int q = lane >> 4, l15 = lane & 15;
  int n0 = blockIdx.x * 128, o0 = blockIdx.y * 128;
  if (t < 128) {
    int o = o0 + t;
    float sc = 0.f, sh = 0.f;
    if (o < O) {
      float b = bias[o];
      if (BN) {
        float g = bnp[o], be = bnp[O + o], m = bnp[2 * O + o], v = bnp[3 * O + o];
        float inv = g * rsqrtf(v + 1e-5f);
        sc = inv; sh = (b - m) * inv + be;
      } else { sc = 1.f; sh = b; }
    }
    scsh[t] = sc; scsh[128 + t] = sh;
  }
  f32x4 acc[4][4] = {};
  for (int c0 = 0; c0 < C; c0 += 32) {
    __syncthreads();
#pragma unroll
    for (int e = 0; e < 2; ++e) {
      int idx = e * 256 + t;
      int row = idx >> 2, kb = idx & 3;
      uint4 xv = *(const uint4*)(X + (size_t)(n0 + row) * C + c0 + kb * 8);
      *(uint4*)&Xs[row * 40 + kb * 8] = xv;
      int go = o0 + row; if (go >= O) go = O - 1;
      uint4 wv = *(const uint4*)(Wb + (size_t)go * C + c0 + kb * 8);
      *(uint4*)&Wl[row * 40 + kb * 8] = wv;
    }
    __syncthreads();
    short8 af[4], bf[4];
#pragma unroll
    for (int a = 0; a < 4; ++a)
      af[a] = *(const short8*)&Wl[(wm * 64 + a * 16 + l15) * 40 + q * 8];
#pragma unroll
    for (int b = 0; b < 4; ++b)
      bf[b] = *(const short8*)&Xs[(wn * 64 + b * 16 + l15) * 40 + q * 8];
#pragma unroll
    for (int a = 0; a < 4; ++a)
#pragma unroll
      for (int b = 0; b < 4; ++b)
        acc[a][b] = __builtin_amdgcn_mfma_f32_16x16x32_bf16(af[a], bf[b], acc[a][b], 0, 0, 0);
  }
  __syncthreads();
  float* lt = (w < 2) ? ((float*)Xs + w * 1280) : ((float*)Wl + (w - 2) * 1280);
#pragma unroll
  for (int a = 0; a < 4; ++a) {
    int oTile = wm * 64 + a * 16;
    if (o0 + oTile >= O) continue;
    float scr[4], shr[4];
#pragma unroll
    for (int r = 0; r < 4; ++r) {
      scr[r] = scsh[oTile + q * 4 + r];
      shr[r] = scsh[128 + oTile + q * 4 + r];
    }
#pragma unroll
    for (int b = 0; b < 4; ++b) {
      int nl = b * 16 + l15;
      f32x4 v;
#pragma unroll
      for (int r = 0; r < 4; ++r) {
        float x = acc[a][b][r] * scr[r] + shr[r];
        if (RELU) x = fmaxf(x, 0.f);
        v[r] = x;
      }
      *(f32x4*)&lt[nl * 20 + q * 4] = v;
    }
#pragma unroll
    for (int g = 0; g < 4; ++g) {
      int nl = g * 16 + (lane >> 2);
      int ob = (lane & 3) * 4;
      f32x4 v = *(const f32x4*)&lt[nl * 20 + ob];
      ushort4 u;
      u.x = f2b(v[0]); u.y = f2b(v[1]); u.z = f2b(v[2]); u.w = f2b(v[3]);
      *(ushort4*)(Y + (size_t)(n0 + wn * 64 + nl) * ldY + o0 + oTile + ob) = u;
    }
  }
}

// ---------------- barrier-free fused back-chain layer: each wave owns 16 rows.
// W A-fragments straight from global (L1/L2-cached, shared by all waves/blocks);
// bias/BN folded per-lane in registers; C/D layout stores ushort4 directly to the
// output LDS rows (no transpose round-trip). Zero __syncthreads.
template <int C, int O, bool BN, bool RELU>
__device__ __forceinline__ void back_layer(const unsigned short* __restrict__ W,
                                           const float* __restrict__ bias,
                                           const float* __restrict__ bnp,
                                           const unsigned short* Xs,
                                           unsigned short* Ys,
                                           int w, int q, int l15) {
  f32x4 acc[O / 16];
#pragma unroll
  for (int i = 0; i < O / 16; ++i) acc[i] = (f32x4){0.f, 0.f, 0.f, 0.f};
#pragma unroll
  for (int k0 = 0; k0 < C; k0 += 32) {
    short8 bf = *(const short8*)&Xs[(w * 16 + l15) * 168 + k0 + q * 8];
#pragma unroll
    for (int ot = 0; ot < O / 16; ++ot) {
      short8 af = *(const short8*)(W + (size_t)(ot * 16 + l15) * C + k0 + q * 8);
      acc[ot] = __builtin_amdgcn_mfma_f32_16x16x32_bf16(af, bf, acc[ot], 0, 0, 0);
    }
  }
#pragma unroll
  for (int ot = 0; ot < O / 16; ++ot) {
    int o4 = ot * 16 + q * 4;
    f32x4 bb = *(const f32x4*)(bias + o4);
    f32x4 sc, sh;
    if (BN) {
      f32x4 g  = *(const f32x4*)(bnp + o4);
      f32x4 be = *(const f32x4*)(bnp + O + o4);
      f32x4 mm = *(const f32x4*)(bnp + 2 * O + o4);
      f32x4 vv = *(const f32x4*)(bnp + 3 * O + o4);
#pragma unroll
      for (int r = 0; r < 4; ++r) {
        float inv = g[r] * rsqrtf(vv[r] + 1e-5f);
        sc[r] = inv; sh[r] = (bb[r] - mm[r]) * inv + be[r];
      }
    } else {
      sc = (f32x4){1.f, 1.f, 1.f, 1.f}; sh = bb;
    }
    ushort4 u;
#pragma unroll
    for (int r = 0; r < 4; ++r) {
      float x = acc[ot][r] * sc[r] + sh[r];
      if (RELU) x = fmaxf(x, 0.f);
      ((unsigned short*)&u)[r] = f2b(x);
    }
    *(ushort4*)&Ys[(w * 16 + l15) * 168 + ot * 16 + q * 4] = u;   // row=n (col=lane&15), col=o (q*4+r)
  }
}

// ---------------- fused back chain: dh1->dh2->dh3->sh1->score/norm/xyz, 64 rows/block
__global__ __launch_bounds__(256) void k_back(const unsigned short* __restrict__ w1,
                                              const unsigned short* __restrict__ w2,
                                              const unsigned short* __restrict__ w3,
                                              const unsigned short* __restrict__ w4,
                                              const float* __restrict__ b1, const float* __restrict__ bn1,
                                              const float* __restrict__ b2, const float* __restrict__ bn2,
                                              const float* __restrict__ b3,
                                              const float* __restrict__ b4, const float* __restrict__ bn4,
                                              const float* __restrict__ wv, const float* __restrict__ bv,
                                              const unsigned short* __restrict__ full,
                                              const float* __restrict__ pxyz,
                                              float* __restrict__ out) {
  __shared__ unsigned short Xb[64 * 168];
  __shared__ unsigned short Yb[64 * 168];
  int t = threadIdx.x, lane = t & 63, w = t >> 6;
  int q = lane >> 4, l15 = lane & 15;
  int n0 = blockIdx.x * 64;
  // per-wave load of its own 16 rows (160 cols = 20 uint4) of `full`
#pragma unroll
  for (int j = 0; j < 5; ++j) {
    int idx = lane + j * 64;               // 0..319
    int row = idx / 20, c8 = idx % 20;
    *(uint4*)&Xb[(w * 16 + row) * 168 + c8 * 8] =
        *(const uint4*)(full + (size_t)(n0 + w * 16 + row) * 160 + c8 * 8);
  }
  back_layer<160, 160, true,  true >(w1, b1, bn1, Xb, Yb, w, q, l15);
  back_layer<160, 160, true,  true >(w2, b2, bn2, Yb, Xb, w, q, l15);
  back_layer<160, 128, false, false>(w3, b3, nullptr, Xb, Yb, w, q, l15); // fp -> Yb
  back_layer<128, 128, true,  true >(w4, b4, bn4, Yb, Xb, w, q, l15);     // s  -> Xb
  // tail (wave-local rows): score from Xb, norm from Yb
  int col8 = (lane & 15) * 8;
  float4 w0 = *(const float4*)(wv + col8);
  float4 wA = *(const float4*)(wv + col8 + 4);
  float bvv = bv[0];
#pragma unroll
  for (int gi = 0; gi < 4; ++gi) {
    int row = w * 16 + gi * 4 + (lane >> 4);
    uint4 raw = *(const uint4*)&Xb[row * 168 + col8];
    float acc = blo(raw.x) * w0.x + bhi(raw.x) * w0.y + blo(raw.y) * w0.z + bhi(raw.y) * w0.w +
                blo(raw.z) * wA.x + bhi(raw.z) * wA.y + blo(raw.w) * wA.z + bhi(raw.w) * wA.w;
    acc += __shfl_xor(acc, 1); acc += __shfl_xor(acc, 2);
    acc += __shfl_xor(acc, 4); acc += __shfl_xor(acc, 8);
    if ((lane & 15) == 0) out[49152 + n0 + row] = 1.f / (1.f + expf(-(acc + bvv)));
    uint4 rf = *(const uint4*)&Yb[row * 168 + col8];
    float v[8] = {blo(rf.x), bhi(rf.x), blo(rf.y), bhi(rf.y),
                  blo(rf.z), bhi(rf.z), blo(rf.w), bhi(rf.w)};
    float s = 0.f;
#pragma unroll
    for (int i = 0; i < 8; ++i) s = fmaf(v[i], v[i], s);
    s += __shfl_xor(s, 1); s += __shfl_xor(s, 2);
    s += __shfl_xor(s, 4); s += __shfl_xor(s, 8);
    float inv = 1.f / fmaxf(sqrtf(s), 1e-12f);
    float* op = out + 65536 + (size_t)(n0 + row) * 128 + col8;
    *(float4*)op = make_float4(v[0] * inv, v[1] * inv, v[2] * inv, v[3] * inv);
    *(float4*)(op + 4) = make_float4(v[4] * inv, v[5] * inv, v[6] * inv, v[7] * inv);
  }
  for (int i = t; i < 192; i += 256) out[n0 * 3 + i] = pxyz[n0 * 3 + i];
}

extern "C" void kernel_launch(void* const* d_in, const int* in_sizes, int n_in,
                              void* d_out, int out_size, void* d_ws, size_t ws_size,
                              hipStream_t stream) {
  const float* pcd_xyz = (const float*)d_in[0];
  const float* rgb_xyz = (const float*)d_in[1];
  const float* pcd_f   = (const float*)d_in[2];
  const float* rgb_f   = (const float*)d_in[3];
  const float* cc1_w = (const float*)d_in[4];  const float* cc1_b = (const float*)d_in[5];
  const float* cc_bn = (const float*)d_in[6];
  const float* cc2_w = (const float*)d_in[7];  const float* cc2_b = (const float*)d_in[8];
  const float* co1_w = (const float*)d_in[9];  const float* co1_b = (const float*)d_in[10];
  const float* co_bn = (const float*)d_in[11];
  const float* co2_w = (const float*)d_in[12]; const float* co2_b = (const float*)d_in[13];
  const float* dh1_w = (const float*)d_in[14]; const float* dh1_b = (const float*)d_in[15];
  const float* dh1_bn = (const float*)d_in[16];
  const float* dh2_w = (const float*)d_in[17]; const float* dh2_b = (const float*)d_in[18];
  const float* dh2_bn = (const float*)d_in[19];
  const float* dh3_w = (const float*)d_in[20]; const float* dh3_b = (const float*)d_in[21];
  const float* sh1_w = (const float*)d_in[22]; const float* sh1_b = (const float*)d_in[23];
  const float* sh_bn = (const float*)d_in[24];
  const float* sh2_w = (const float*)d_in[25]; const float* sh2_b = (const float*)d_in[26];

  char* ws = (char*)d_ws;
  float* out = (float*)d_out;

  unsigned short* wb    = (unsigned short*)(ws);              // 766 KB
  unsigned short* rgbTb = (unsigned short*)(ws + 0x100000);   // 2.1 MB
  float4* rxyz4         = (float4*)(ws + 0x320000);           // 128 KB
  float* pd  = (float*)(ws + 0x400000);                       // 1.5 MB
  int*   pi  = (int*)(ws + 0x700000);                         // 1.5 MB
  unsigned short* xcat = (unsigned short*)(ws + 0xA00000);    // (NP,384)
  unsigned short* h1   = (unsigned short*)(ws + 0x1700000);   // (NP,384)
  unsigned short* x2   = (unsigned short*)(ws + 0x2300000);   // (NP,256)
  unsigned short* h2   = (unsigned short*)(ws + 0x2B00000);   // (NP,256)
  unsigned short* full = (unsigned short*)(ws + 0x3300000);   // (NP,160)

  unsigned short* wb_cc1 = wb;
  unsigned short* wb_cc2 = wb + 147456;
  unsigned short* wb_co1 = wb + 196608;
  unsigned short* wb_co2 = wb + 262144;
  unsigned short* wb_dh1 = wb + 294912;
  unsigned short* wb_dh2 = wb + 320512;
  unsigned short* wb_dh3 = wb + 346112;
  unsigned short* wb_sh1 = wb + 366592;

  k_pre<<<960, 256, 0, stream>>>(rgb_f, rgb_xyz, pcd_f,
                                 cc1_w, cc2_w, co1_w, co2_w, dh1_w, dh2_w, dh3_w, sh1_w,
                                 rgbTb, rxyz4, full, wb);
  k_nn_part<<<dim3(256, 8), 256, 0, stream>>>(pcd_xyz, rxyz4, pd, pi);
  k_gather_max<<<4096, 256, 0, stream>>>(rgbTb, pd, pi, xcat, x2);

  k_bgemm<true, true><<<dim3(128, 3), 256, 0, stream>>>(wb_cc1, cc1_b, cc_bn, xcat, h1, 384, 384, 384);
  k_bgemm<false, false><<<dim3(128, 1), 256, 0, stream>>>(wb_cc2, cc2_b, nullptr, h1, x2, 128, 384, 256);
  k_bgemm<true, true><<<dim3(128, 2), 256, 0, stream>>>(wb_co1, co1_b, co_bn, x2, h2, 256, 256, 256);
  k_bgemm<false, false><<<dim3(128, 1), 256, 0, stream>>>(wb_co2, co2_b, nullptr, h2, full + 32, 128, 256, 160);

  k_back<<<256, 256, 0, stream>>>(wb_dh1, wb_dh2, wb_dh3, wb_sh1,
                                  dh1_b, dh1_bn, dh2_b, dh2_bn, dh3_b, sh1_b, sh_bn,
                                  sh2_w, sh2_b, full, pcd_xyz, out);
}

// Round 9
// 233.636 us; speedup vs baseline: 1.1285x; 1.1285x over previous
//
#include <hip/hip_runtime.h>
#include <math.h>

#define NP 16384
#define NR 8192

typedef __attribute__((ext_vector_type(8))) short short8;
typedef __attribute__((ext_vector_type(4))) float f32x4;

__device__ inline unsigned short f2b(float f) {
  unsigned int x = __float_as_uint(f);
  return (unsigned short)((x + 0x7FFFu + ((x >> 16) & 1u)) >> 16);  // RNE
}
__device__ inline float blo(unsigned int u) { return __uint_as_float(u << 16); }
__device__ inline float bhi(unsigned int u) { return __uint_as_float(u & 0xffff0000u); }

// ---------------- fused preprocessing: blocks 0..127 rgb transpose (+rxyz4 pack),
// 128..383 pcd transpose, 384..959 weight f32->bf16 conversion
__global__ __launch_bounds__(256) void k_pre(const float* __restrict__ rf,
                                             const float* __restrict__ rxyz,
                                             const float* __restrict__ pf,
                                             const float* __restrict__ s0, const float* __restrict__ s1,
                                             const float* __restrict__ s2, const float* __restrict__ s3,
                                             const float* __restrict__ s4, const float* __restrict__ s5,
                                             const float* __restrict__ s6, const float* __restrict__ s7,
                                             unsigned short* __restrict__ rgbTb,
                                             float4* __restrict__ rxyz4,
                                             unsigned short* __restrict__ full,
                                             unsigned short* __restrict__ dst) {
  __shared__ float tile[128][65];
  int b = blockIdx.x, t = threadIdx.x;
  if (b < 128) {
    int r0 = b * 64;
    for (int e = 0; e < 32; ++e) {
      int idx = t + e * 256;
      int c = idx >> 6, rl = idx & 63;
      tile[c][rl] = rf[c * NR + r0 + rl];
    }
    __syncthreads();
    for (int e = 0; e < 32; ++e) {
      int idx = t + e * 256;
      int rl = idx >> 7, c = idx & 127;
      rgbTb[(size_t)(r0 + rl) * 128 + c] = f2b(tile[c][rl]);
    }
    if (b == 0 && t < 128) rgbTb[(size_t)NR * 128 + t] = 0;
    if ((t >> 6) == 0) {
      int i = r0 + (t & 63);
      float x = rxyz[i * 3], y = rxyz[i * 3 + 1], z = rxyz[i * 3 + 2];
      rxyz4[i] = make_float4(x, y, z, fmaf(x, x, fmaf(y, y, z * z)));
    }
  } else if (b < 384) {
    int n0 = (b - 128) * 64;
    for (int e = 0; e < 8; ++e) {
      int idx = t + e * 256;
      int c = idx >> 6, nl = idx & 63;
      tile[c][nl] = pf[c * NP + n0 + nl];
    }
    __syncthreads();
    for (int e = 0; e < 8; ++e) {
      int idx = t + e * 256;
      int nl = idx >> 5, c = idx & 31;
      full[(size_t)(n0 + nl) * 160 + c] = f2b(tile[c][nl]);
    }
  } else {
    const int sizes[8] = {147456, 49152, 65536, 32768, 25600, 25600, 20480, 16384};
    const int offs[8]  = {0, 147456, 196608, 262144, 294912, 320512, 346112, 366592};
    const float* srcs[8] = {s0, s1, s2, s3, s4, s5, s6, s7};
    int j = b - 384;
    int m = j / 72, bx = j % 72;
    int i = (bx * 256 + t) * 8;
    if (i >= sizes[m]) return;
    const float4* sp = (const float4*)(srcs[m] + i);
    float4 a = sp[0], c = sp[1];
    uint4 o;
    o.x = f2b(a.x) | ((unsigned int)f2b(a.y) << 16);
    o.y = f2b(a.z) | ((unsigned int)f2b(a.w) << 16);
    o.z = f2b(c.x) | ((unsigned int)f2b(c.y) << 16);
    o.w = f2b(c.z) | ((unsigned int)f2b(c.w) << 16);
    *(uint4*)(dst + offs[m] + i) = o;
  }
}

// ---------------- three_nn partials (unchanged, R6-verified)
__global__ __launch_bounds__(256) void k_nn_part(const float* __restrict__ pxyz,
                                                 const float4* __restrict__ rxyz4,
                                                 float* __restrict__ pd,
                                                 int* __restrict__ pi) {
  __shared__ float4 pts[1024];
  __shared__ float msd[4][3][64];
  __shared__ int   mid[4][3][64];
  int t = threadIdx.x;
  int g = blockIdx.x, s = blockIdx.y;
  int lane = t & 63, w = t >> 6;
  int rbase = s * 1024;
#pragma unroll
  for (int e = 0; e < 4; ++e) {
    int q = t + e * 256;
    pts[q] = rxyz4[rbase + q];
  }
  int n = g * 64 + lane;
  float px = pxyz[n * 3], py = pxyz[n * 3 + 1], pz = pxyz[n * 3 + 2];
  float pp = fmaf(px, px, fmaf(py, py, pz * pz));
  float nx2 = -2.f * px, ny2 = -2.f * py, nz2 = -2.f * pz;
  __syncthreads();
  const float R2L = 0.005626125f;          // 0.075^2 * 1.0002 sentinel (> R2 -> masks to NR)
  const float MARGIN = 4e-6f;              // covers fp32 error of expanded form
  float s0 = R2L, s1 = R2L, s2 = R2L;
  int i0 = 0, i1 = 0, i2 = 0;
  float thr = R2L + MARGIN - pp;
  int base = w * 256;
#pragma unroll 8
  for (int loc = 0; loc < 256; ++loc) {
    float4 r = pts[base + loc];            // wave-uniform address -> LDS broadcast
    float e3 = fmaf(nz2, r.z, fmaf(ny2, r.y, fmaf(nx2, r.x, r.w)));
    if (__ballot(e3 < thr)) {              // wave-uniform branch
      float dx = px - r.x, dy = py - r.y, dz = pz - r.z;
      float d2 = fmaf(dx, dx, fmaf(dy, dy, dz * dz));
      if (d2 < s2) {                       // exact strict <: reference tie-break
        int i = rbase + base + loc;
        if (d2 < s1) {
          s2 = s1; i2 = i1;
          if (d2 < s0) { s1 = s0; i1 = i0; s0 = d2; i0 = i; }
          else         { s1 = d2; i1 = i; }
        } else { s2 = d2; i2 = i; }
      }
      thr = s2 + MARGIN - pp;
    }
  }
  msd[w][0][lane] = s0; msd[w][1][lane] = s1; msd[w][2][lane] = s2;
  mid[w][0][lane] = i0; mid[w][1][lane] = i1; mid[w][2][lane] = i2;
  __syncthreads();
  if (t < 64) {
    s0 = msd[0][0][t]; s1 = msd[0][1][t]; s2 = msd[0][2][t];
    i0 = mid[0][0][t]; i1 = mid[0][1][t]; i2 = mid[0][2][t];
    for (int ww = 1; ww < 4; ++ww) {       // ascending candidate order
      for (int q = 0; q < 3; ++q) {
        float d2 = msd[ww][q][t]; int i = mid[ww][q][t];
        if (d2 < s2) {
          if (d2 < s1) {
            s2 = s1; i2 = i1;
            if (d2 < s0) { s1 = s0; i1 = i0; s0 = d2; i0 = i; }
            else         { s1 = d2; i1 = i; }
          } else { s2 = d2; i2 = i; }
        }
      }
    }
    int off = ((g * 8 + s) * 64 + t) * 3;
    pd[off + 0] = s0; pd[off + 1] = s1; pd[off + 2] = s2;
    pi[off + 0] = i0; pi[off + 1] = i1; pi[off + 2] = i2;
  }
}

// ---------------- fused merge + gather + max (unchanged, R7-verified)
__global__ __launch_bounds__(256) void k_gather_max(const unsigned short* __restrict__ rgbTb,
                                                    const float* __restrict__ pd,
                                                    const int* __restrict__ pi,
                                                    unsigned short* __restrict__ xcat,
                                                    unsigned short* __restrict__ x2) {
  int t = threadIdx.x, lane = t & 63, w = t >> 6;
  int n = blockIdx.x * 4 + w;
  int g = n >> 6, l = n & 63;
  unsigned long long key = ~0ull;
  if (lane < 24) {
    int s = lane / 3, qq = lane % 3;
    int off = ((g * 8 + s) * 64 + l) * 3 + qq;
    key = ((unsigned long long)__float_as_uint(pd[off]) << 32) | (unsigned int)pi[off];
  }
  unsigned long long mk[3];
#pragma unroll
  for (int r = 0; r < 3; ++r) {
    unsigned long long m = key;
#pragma unroll
    for (int o = 1; o < 64; o <<= 1) {
      unsigned long long other = __shfl_xor(m, o);
      m = other < m ? other : m;
    }
    mk[r] = m;
    if (key == m) key = ~0ull;
  }
  const float R2 = 0.075f * 0.075f;
  float d0 = __uint_as_float((unsigned int)(mk[0] >> 32));
  float d1 = __uint_as_float((unsigned int)(mk[1] >> 32));
  float d2 = __uint_as_float((unsigned int)(mk[2] >> 32));
  int j0 = (d0 > R2) ? NR : (int)(mk[0] & 0xffffffffu);
  int j1 = (d1 > R2) ? NR : (int)(mk[1] & 0xffffffffu);
  int j2 = (d2 > R2) ? NR : (int)(mk[2] & 0xffffffffu);
  unsigned int a = ((const unsigned int*)(rgbTb + (size_t)j0 * 128))[lane];
  unsigned int b = ((const unsigned int*)(rgbTb + (size_t)j1 * 128))[lane];
  unsigned int c = ((const unsigned int*)(rgbTb + (size_t)j2 * 128))[lane];
  unsigned int* xr = (unsigned int*)(xcat + (size_t)n * 384);
  xr[lane] = a; xr[64 + lane] = b; xr[128 + lane] = c;
  float ml = fmaxf(blo(a), fmaxf(blo(b), blo(c)));
  float mh = fmaxf(bhi(a), fmaxf(bhi(b), bhi(c)));
  unsigned int m = (__float_as_uint(mh) & 0xffff0000u) | (__float_as_uint(ml) >> 16);
  ((unsigned int*)(x2 + (size_t)n * 256 + 128))[lane] = m;
}

// ---------------- bf16 MFMA GEMM (unchanged, front chain only)
template <bool BN, bool RELU>
__global__ __launch_bounds__(256) void k_bgemm(const unsigned short* __restrict__ Wb,
                                               const float* __restrict__ bias,
                                               const float* __restrict__ bnp,
                                               const unsigned short* __restrict__ X,
                                               unsigned short* __restrict__ Y,
                                               int O, int C, int ldY) {
  __shared__ unsigned short Xs[128 * 40];
  __shared__ unsigned short Wl[128 * 40];
  __shared__ float scsh[256];
  int t = threadIdx.x;
  int lane = t & 63, w = t >> 6;
  int wn = w & 1, wm = w >> 1;
  int q = lane >> 4, l15 = lane & 15;
  int n0 = blockIdx.x * 128, o0 = blockIdx.y * 128;
  if (t < 128) {
    int o = o0 + t;
    float sc = 0.f, sh = 0.f;
    if (o < O) {
      float b = bias[o];
      if (BN) {
        float g = bnp[o], be = bnp[O + o], m = bnp[2 * O + o], v = bnp[3 * O + o];
        float inv = g * rsqrtf(v + 1e-5f);
        sc = inv; sh = (b - m) * inv + be;
      } else { sc = 1.f; sh = b; }
    }
    scsh[t] = sc; scsh[128 + t] = sh;
  }
  f32x4 acc[4][4] = {};
  for (int c0 = 0; c0 < C; c0 += 32) {
    __syncthreads();
#pragma unroll
    for (int e = 0; e < 2; ++e) {
      int idx = e * 256 + t;
      int row = idx >> 2, kb = idx & 3;
      uint4 xv = *(const uint4*)(X + (size_t)(n0 + row) * C + c0 + kb * 8);
      *(uint4*)&Xs[row * 40 + kb * 8] = xv;
      int go = o0 + row; if (go >= O) go = O - 1;
      uint4 wv = *(const uint4*)(Wb + (size_t)go * C + c0 + kb * 8);
      *(uint4*)&Wl[row * 40 + kb * 8] = wv;
    }
    __syncthreads();
    short8 af[4], bf[4];
#pragma unroll
    for (int a = 0; a < 4; ++a)
      af[a] = *(const short8*)&Wl[(wm * 64 + a * 16 + l15) * 40 + q * 8];
#pragma unroll
    for (int b = 0; b < 4; ++b)
      bf[b] = *(const short8*)&Xs[(wn * 64 + b * 16 + l15) * 40 + q * 8];
#pragma unroll
    for (int a = 0; a < 4; ++a)
#pragma unroll
      for (int b = 0; b < 4; ++b)
        acc[a][b] = __builtin_amdgcn_mfma_f32_16x16x32_bf16(af[a], bf[b], acc[a][b], 0, 0, 0);
  }
  __syncthreads();
  float* lt = (w < 2) ? ((float*)Xs + w * 1280) : ((float*)Wl + (w - 2) * 1280);
#pragma unroll
  for (int a = 0; a < 4; ++a) {
    int oTile = wm * 64 + a * 16;
    if (o0 + oTile >= O) continue;
    float scr[4], shr[4];
#pragma unroll
    for (int r = 0; r < 4; ++r) {
      scr[r] = scsh[oTile + q * 4 + r];
      shr[r] = scsh[128 + oTile + q * 4 + r];
    }
#pragma unroll
    for (int b = 0; b < 4; ++b) {
      int nl = b * 16 + l15;
      f32x4 v;
#pragma unroll
      for (int r = 0; r < 4; ++r) {
        float x = acc[a][b][r] * scr[r] + shr[r];
        if (RELU) x = fmaxf(x, 0.f);
        v[r] = x;
      }
      *(f32x4*)&lt[nl * 20 + q * 4] = v;
    }
#pragma unroll
    for (int g = 0; g < 4; ++g) {
      int nl = g * 16 + (lane >> 2);
      int ob = (lane & 3) * 4;
      f32x4 v = *(const f32x4*)&lt[nl * 20 + ob];
      ushort4 u;
      u.x = f2b(v[0]); u.y = f2b(v[1]); u.z = f2b(v[2]); u.w = f2b(v[3]);
      *(ushort4*)(Y + (size_t)(n0 + wn * 64 + nl) * ldY + o0 + oTile + ob) = u;
    }
  }
}

// ---------------- back-chain layer, o-split across 4 waves: wave w computes output
// tiles ot = w, w+4, ... All 16 activation rows shared in LDS; W A-fragments from
// global (L2-hot, <=15 loads/wave/layer); bias/BN folded per-lane; C/D layout stores
// ushort4 straight into the output LDS rows. Caller barriers between layers.
template <int C, int O, bool BN, bool RELU>
__device__ __forceinline__ void back_layer(const unsigned short* __restrict__ W,
                                           const float* __restrict__ bias,
                                           const float* __restrict__ bnp,
                                           const unsigned short* Xs,
                                           unsigned short* Ys,
                                           int w, int q, int l15) {
  constexpr int NT = O / 16;
  constexpr int MT = (NT + 3) / 4;
  f32x4 acc[MT];
#pragma unroll
  for (int i = 0; i < MT; ++i) acc[i] = (f32x4){0.f, 0.f, 0.f, 0.f};
#pragma unroll
  for (int k0 = 0; k0 < C; k0 += 32) {
    short8 bf = *(const short8*)&Xs[l15 * 168 + k0 + q * 8];
#pragma unroll
    for (int i = 0; i < MT; ++i) {
      int ot = w + i * 4;
      if (ot < NT) {
        short8 af = *(const short8*)(W + (size_t)(ot * 16 + l15) * C + k0 + q * 8);
        acc[i] = __builtin_amdgcn_mfma_f32_16x16x32_bf16(af, bf, acc[i], 0, 0, 0);
      }
    }
  }
#pragma unroll
  for (int i = 0; i < MT; ++i) {
    int ot = w + i * 4;
    if (ot >= NT) continue;
    int o4 = ot * 16 + q * 4;
    f32x4 bb = *(const f32x4*)(bias + o4);
    f32x4 sc, sh;
    if (BN) {
      f32x4 g  = *(const f32x4*)(bnp + o4);
      f32x4 be = *(const f32x4*)(bnp + O + o4);
      f32x4 mm = *(const f32x4*)(bnp + 2 * O + o4);
      f32x4 vv = *(const f32x4*)(bnp + 3 * O + o4);
#pragma unroll
      for (int r = 0; r < 4; ++r) {
        float inv = g[r] * rsqrtf(vv[r] + 1e-5f);
        sc[r] = inv; sh[r] = (bb[r] - mm[r]) * inv + be[r];
      }
    } else {
      sc = (f32x4){1.f, 1.f, 1.f, 1.f}; sh = bb;
    }
    ushort4 u;
#pragma unroll
    for (int r = 0; r < 4; ++r) {
      float x = acc[i][r] * sc[r] + sh[r];
      if (RELU) x = fmaxf(x, 0.f);
      ((unsigned short*)&u)[r] = f2b(x);
    }
    *(ushort4*)&Ys[l15 * 168 + ot * 16 + q * 4] = u;   // row=n (lane&15), col=o (q*4+r)
  }
}

// ---------------- fused back chain: 16 rows/block, 1024 blocks (4 blocks/CU, 16 waves/CU)
__global__ __launch_bounds__(256) void k_back(const unsigned short* __restrict__ w1,
                                              const unsigned short* __restrict__ w2,
                                              const unsigned short* __restrict__ w3,
                                              const unsigned short* __restrict__ w4,
                                              const float* __restrict__ b1, const float* __restrict__ bn1,
                                              const float* __restrict__ b2, const float* __restrict__ bn2,
                                              const float* __restrict__ b3,
                                              const float* __restrict__ b4, const float* __restrict__ bn4,
                                              const float* __restrict__ wv, const float* __restrict__ bv,
                                              const unsigned short* __restrict__ full,
                                              const float* __restrict__ pxyz,
                                              float* __restrict__ out) {
  __shared__ unsigned short Xb[16 * 168];
  __shared__ unsigned short Yb[16 * 168];
  int t = threadIdx.x, lane = t & 63, w = t >> 6;
  int q = lane >> 4, l15 = lane & 15;
  int n0 = blockIdx.x * 16;
  for (int idx = t; idx < 320; idx += 256) {      // 16 rows x 20 uint4
    int row = idx / 20, c8 = idx % 20;
    *(uint4*)&Xb[row * 168 + c8 * 8] = *(const uint4*)(full + (size_t)(n0 + row) * 160 + c8 * 8);
  }
  __syncthreads();
  back_layer<160, 160, true,  true >(w1, b1, bn1, Xb, Yb, w, q, l15);
  __syncthreads();
  back_layer<160, 160, true,  true >(w2, b2, bn2, Yb, Xb, w, q, l15);
  __syncthreads();
  back_layer<160, 128, false, false>(w3, b3, nullptr, Xb, Yb, w, q, l15); // fp -> Yb
  __syncthreads();
  back_layer<128, 128, true,  true >(w4, b4, bn4, Yb, Xb, w, q, l15);     // s  -> Xb
  __syncthreads();
  // tail: wave w handles rows w*4 .. w*4+3 (row = w*4 + lane/16)
  int col8 = (lane & 15) * 8;
  float4 w0 = *(const float4*)(wv + col8);
  float4 wA = *(const float4*)(wv + col8 + 4);
  float bvv = bv[0];
  int row = w * 4 + (lane >> 4);
  uint4 raw = *(const uint4*)&Xb[row * 168 + col8];
  float acc = blo(raw.x) * w0.x + bhi(raw.x) * w0.y + blo(raw.y) * w0.z + bhi(raw.y) * w0.w +
              blo(raw.z) * wA.x + bhi(raw.z) * wA.y + blo(raw.w) * wA.z + bhi(raw.w) * wA.w;
  acc += __shfl_xor(acc, 1); acc += __shfl_xor(acc, 2);
  acc += __shfl_xor(acc, 4); acc += __shfl_xor(acc, 8);
  if ((lane & 15) == 0) out[49152 + n0 + row] = 1.f / (1.f + expf(-(acc + bvv)));
  uint4 rf = *(const uint4*)&Yb[row * 168 + col8];
  float v[8] = {blo(rf.x), bhi(rf.x), blo(rf.y), bhi(rf.y),
                blo(rf.z), bhi(rf.z), blo(rf.w), bhi(rf.w)};
  float s = 0.f;
#pragma unroll
  for (int i = 0; i < 8; ++i) s = fmaf(v[i], v[i], s);
  s += __shfl_xor(s, 1); s += __shfl_xor(s, 2);
  s += __shfl_xor(s, 4); s += __shfl_xor(s, 8);
  float inv = 1.f / fmaxf(sqrtf(s), 1e-12f);
  float* op = out + 65536 + (size_t)(n0 + row) * 128 + col8;
  *(float4*)op = make_float4(v[0] * inv, v[1] * inv, v[2] * inv, v[3] * inv);
  *(float4*)(op + 4) = make_float4(v[4] * inv, v[5] * inv, v[6] * inv, v[7] * inv);
  for (int i = t; i < 48; i += 256) out[n0 * 3 + i] = pxyz[n0 * 3 + i];
}

extern "C" void kernel_launch(void* const* d_in, const int* in_sizes, int n_in,
                              void* d_out, int out_size, void* d_ws, size_t ws_size,
                              hipStream_t stream) {
  const float* pcd_xyz = (const float*)d_in[0];
  const float* rgb_xyz = (const float*)d_in[1];
  const float* pcd_f   = (const float*)d_in[2];
  const float* rgb_f   = (const float*)d_in[3];
  const float* cc1_w = (const float*)d_in[4];  const float* cc1_b = (const float*)d_in[5];
  const float* cc_bn = (const float*)d_in[6];
  const float* cc2_w = (const float*)d_in[7];  const float* cc2_b = (const float*)d_in[8];
  const float* co1_w = (const float*)d_in[9];  const float* co1_b = (const float*)d_in[10];
  const float* co_bn = (const float*)d_in[11];
  const float* co2_w = (const float*)d_in[12]; const float* co2_b = (const float*)d_in[13];
  const float* dh1_w = (const float*)d_in[14]; const float* dh1_b = (const float*)d_in[15];
  const float* dh1_bn = (const float*)d_in[16];
  const float* dh2_w = (const float*)d_in[17]; const float* dh2_b = (const float*)d_in[18];
  const float* dh2_bn = (const float*)d_in[19];
  const float* dh3_w = (const float*)d_in[20]; const float* dh3_b = (const float*)d_in[21];
  const float* sh1_w = (const float*)d_in[22]; const float* sh1_b = (const float*)d_in[23];
  const float* sh_bn = (const float*)d_in[24];
  const float* sh2_w = (const float*)d_in[25]; const float* sh2_b = (const float*)d_in[26];

  char* ws = (char*)d_ws;
  float* out = (float*)d_out;

  unsigned short* wb    = (unsigned short*)(ws);              // 766 KB
  unsigned short* rgbTb = (unsigned short*)(ws + 0x100000);   // 2.1 MB
  float4* rxyz4         = (float4*)(ws + 0x320000);           // 128 KB
  float* pd  = (float*)(ws + 0x400000);                       // 1.5 MB
  int*   pi  = (int*)(ws + 0x700000);                         // 1.5 MB
  unsigned short* xcat = (unsigned short*)(ws + 0xA00000);    // (NP,384)
  unsigned short* h1   = (unsigned short*)(ws + 0x1700000);   // (NP,384)
  unsigned short* x2   = (unsigned short*)(ws + 0x2300000);   // (NP,256)
  unsigned short* h2   = (unsigned short*)(ws + 0x2B00000);   // (NP,256)
  unsigned short* full = (unsigned short*)(ws + 0x3300000);   // (NP,160)

  unsigned short* wb_cc1 = wb;
  unsigned short* wb_cc2 = wb + 147456;
  unsigned short* wb_co1 = wb + 196608;
  unsigned short* wb_co2 = wb + 262144;
  unsigned short* wb_dh1 = wb + 294912;
  unsigned short* wb_dh2 = wb + 320512;
  unsigned short* wb_dh3 = wb + 346112;
  unsigned short* wb_sh1 = wb + 366592;

  k_pre<<<960, 256, 0, stream>>>(rgb_f, rgb_xyz, pcd_f,
                                 cc1_w, cc2_w, co1_w, co2_w, dh1_w, dh2_w, dh3_w, sh1_w,
                                 rgbTb, rxyz4, full, wb);
  k_nn_part<<<dim3(256, 8), 256, 0, stream>>>(pcd_xyz, rxyz4, pd, pi);
  k_gather_max<<<4096, 256, 0, stream>>>(rgbTb, pd, pi, xcat, x2);

  k_bgemm<true, true><<<dim3(128, 3), 256, 0, stream>>>(wb_cc1, cc1_b, cc_bn, xcat, h1, 384, 384, 384);
  k_bgemm<false, false><<<dim3(128, 1), 256, 0, stream>>>(wb_cc2, cc2_b, nullptr, h1, x2, 128, 384, 256);
  k_bgemm<true, true><<<dim3(128, 2), 256, 0, stream>>>(wb_co1, co1_b, co_bn, x2, h2, 256, 256, 256);
  k_bgemm<false, false><<<dim3(128, 1), 256, 0, stream>>>(wb_co2, co2_b, nullptr, h2, full + 32, 128, 256, 160);

  k_back<<<1024, 256, 0, stream>>>(wb_dh1, wb_dh2, wb_dh3, wb_sh1,
                                   dh1_b, dh1_bn, dh2_b, dh2_bn, dh3_b, sh1_b, sh_bn,
                                   sh2_w, sh2_b, full, pcd_xyz, out);
}

// Round 10
// 233.310 us; speedup vs baseline: 1.1301x; 1.0014x over previous
//
#include <hip/hip_runtime.h>
#include <math.h>

#define NP 16384
#define NR 8192

typedef __attribute__((ext_vector_type(8))) short short8;
typedef __attribute__((ext_vector_type(4))) float f32x4;

__device__ inline unsigned short f2b(float f) {
  unsigned int x = __float_as_uint(f);
  return (unsigned short)((x + 0x7FFFu + ((x >> 16) & 1u)) >> 16);  // RNE
}
__device__ inline float blo(unsigned int u) { return __uint_as_float(u << 16); }
__device__ inline float bhi(unsigned int u) { return __uint_as_float(u & 0xffff0000u); }

// ---------------- fused preprocessing: blocks 0..127 rgb transpose (+rxyz4 pack),
// 128..383 pcd transpose, 384..959 weight f32->bf16 conversion
__global__ __launch_bounds__(256) void k_pre(const float* __restrict__ rf,
                                             const float* __restrict__ rxyz,
                                             const float* __restrict__ pf,
                                             const float* __restrict__ s0, const float* __restrict__ s1,
                                             const float* __restrict__ s2, const float* __restrict__ s3,
                                             const float* __restrict__ s4, const float* __restrict__ s5,
                                             const float* __restrict__ s6, const float* __restrict__ s7,
                                             unsigned short* __restrict__ rgbTb,
                                             float4* __restrict__ rxyz4,
                                             unsigned short* __restrict__ full,
                                             unsigned short* __restrict__ dst) {
  __shared__ float tile[128][65];
  int b = blockIdx.x, t = threadIdx.x;
  if (b < 128) {
    int r0 = b * 64;
    for (int e = 0; e < 32; ++e) {
      int idx = t + e * 256;
      int c = idx >> 6, rl = idx & 63;
      tile[c][rl] = rf[c * NR + r0 + rl];
    }
    __syncthreads();
    for (int e = 0; e < 32; ++e) {
      int idx = t + e * 256;
      int rl = idx >> 7, c = idx & 127;
      rgbTb[(size_t)(r0 + rl) * 128 + c] = f2b(tile[c][rl]);
    }
    if (b == 0 && t < 128) rgbTb[(size_t)NR * 128 + t] = 0;
    if ((t >> 6) == 0) {
      int i = r0 + (t & 63);
      float x = rxyz[i * 3], y = rxyz[i * 3 + 1], z = rxyz[i * 3 + 2];
      rxyz4[i] = make_float4(x, y, z, fmaf(x, x, fmaf(y, y, z * z)));
    }
  } else if (b < 384) {
    int n0 = (b - 128) * 64;
    for (int e = 0; e < 8; ++e) {
      int idx = t + e * 256;
      int c = idx >> 6, nl = idx & 63;
      tile[c][nl] = pf[c * NP + n0 + nl];
    }
    __syncthreads();
    for (int e = 0; e < 8; ++e) {
      int idx = t + e * 256;
      int nl = idx >> 5, c = idx & 31;
      full[(size_t)(n0 + nl) * 160 + c] = f2b(tile[c][nl]);
    }
  } else {
    const int sizes[8] = {147456, 49152, 65536, 32768, 25600, 25600, 20480, 16384};
    const int offs[8]  = {0, 147456, 196608, 262144, 294912, 320512, 346112, 366592};
    const float* srcs[8] = {s0, s1, s2, s3, s4, s5, s6, s7};
    int j = b - 384;
    int m = j / 72, bx = j % 72;
    int i = (bx * 256 + t) * 8;
    if (i >= sizes[m]) return;
    const float4* sp = (const float4*)(srcs[m] + i);
    float4 a = sp[0], c = sp[1];
    uint4 o;
    o.x = f2b(a.x) | ((unsigned int)f2b(a.y) << 16);
    o.y = f2b(a.z) | ((unsigned int)f2b(a.w) << 16);
    o.z = f2b(c.x) | ((unsigned int)f2b(c.y) << 16);
    o.w = f2b(c.z) | ((unsigned int)f2b(c.w) << 16);
    *(uint4*)(dst + offs[m] + i) = o;
  }
}

// ---------------- three_nn partials, 4 points/lane: each ds_read_b128 broadcast is
// amortized over 4 filter evaluations (the DS pipe was the R9 ceiling: 8192 reads/CU
// x 12 cyc = 41 us; now 2048/CU). Grid (64 groups x 16 splits), 4 waves scan 128-cand
// sub-chunks of the split; intra-block merge over 256 points. Exact d2 in the rare
// path is bit-identical to the verified R6 kernel (dx = fmaf(0.5,nx2,r.x) == r.x-px
// exactly; squares kill the sign). Sentinel/tie-break semantics unchanged.
__global__ __launch_bounds__(256) void k_nn_part(const float* __restrict__ pxyz,
                                                 const float4* __restrict__ rxyz4,
                                                 float* __restrict__ pd,
                                                 int* __restrict__ pi) {
  __shared__ float4 pts[512];              // 8 KB
  __shared__ float msd[4][3][256];         // 12 KB
  __shared__ int   mid[4][3][256];         // 12 KB
  int t = threadIdx.x;
  int g = blockIdx.x, s = blockIdx.y;      // g in [0,64), s in [0,16)
  int lane = t & 63, w = t >> 6;
  int rbase = s * 512;
#pragma unroll
  for (int e = 0; e < 2; ++e) pts[t + e * 256] = rxyz4[rbase + t + e * 256];
  const float R2L = 0.005626125f;          // 0.075^2 * 1.0002 sentinel (> R2 -> masks to NR)
  const float MARGIN = 4e-6f;              // covers fp32 error of expanded form
  float nx2[4], ny2[4], nz2[4], pp[4], thr[4];
  float s0[4], s1[4], s2[4];
  int i0[4], i1[4], i2[4];
#pragma unroll
  for (int j = 0; j < 4; ++j) {
    int n = g * 256 + j * 64 + lane;
    float px = pxyz[n * 3], py = pxyz[n * 3 + 1], pz = pxyz[n * 3 + 2];
    pp[j] = fmaf(px, px, fmaf(py, py, pz * pz));
    nx2[j] = -2.f * px; ny2[j] = -2.f * py; nz2[j] = -2.f * pz;
    s0[j] = R2L; s1[j] = R2L; s2[j] = R2L;
    i0[j] = 0; i1[j] = 0; i2[j] = 0;
    thr[j] = R2L + MARGIN - pp[j];
  }
  __syncthreads();
  int base = w * 128;
#pragma unroll 4
  for (int loc = 0; loc < 128; ++loc) {
    float4 r = pts[base + loc];            // wave-uniform address -> LDS broadcast
    int idx = rbase + base + loc;
#pragma unroll
    for (int j = 0; j < 4; ++j) {
      float e3 = fmaf(nz2[j], r.z, fmaf(ny2[j], r.y, fmaf(nx2[j], r.x, r.w)));
      if (__ballot(e3 < thr[j])) {         // wave-uniform branch, rarely taken (~11%)
        float dx = fmaf(0.5f, nx2[j], r.x);   // == r.x - px exactly
        float dy = fmaf(0.5f, ny2[j], r.y);
        float dz = fmaf(0.5f, nz2[j], r.z);
        float d2 = fmaf(dx, dx, fmaf(dy, dy, dz * dz));
        if (d2 < s2[j]) {                  // exact strict <: reference tie-break
          if (d2 < s1[j]) {
            s2[j] = s1[j]; i2[j] = i1[j];
            if (d2 < s0[j]) { s1[j] = s0[j]; i1[j] = i0[j]; s0[j] = d2; i0[j] = idx; }
            else            { s1[j] = d2; i1[j] = idx; }
          } else { s2[j] = d2; i2[j] = idx; }
        }
        thr[j] = s2[j] + MARGIN - pp[j];
      }
    }
  }
#pragma unroll
  for (int j = 0; j < 4; ++j) {
    int pl = j * 64 + lane;
    msd[w][0][pl] = s0[j]; msd[w][1][pl] = s1[j]; msd[w][2][pl] = s2[j];
    mid[w][0][pl] = i0[j]; mid[w][1][pl] = i1[j]; mid[w][2][pl] = i2[j];
  }
  __syncthreads();
  {                                         // t handles point t of the 256
    float a0 = msd[0][0][t], a1 = msd[0][1][t], a2 = msd[0][2][t];
    int b0 = mid[0][0][t], b1 = mid[0][1][t], b2 = mid[0][2][t];
    for (int ww = 1; ww < 4; ++ww) {        // ascending candidate order: tie-break correct
      for (int q = 0; q < 3; ++q) {
        float d2 = msd[ww][q][t]; int i = mid[ww][q][t];
        if (d2 < a2) {
          if (d2 < a1) {
            a2 = a1; b2 = b1;
            if (d2 < a0) { a1 = a0; b1 = b0; a0 = d2; b0 = i; }
            else         { a1 = d2; b1 = i; }
          } else { a2 = d2; b2 = i; }
        }
      }
    }
    int off = ((g * 16 + s) * 256 + t) * 3;
    pd[off + 0] = a0; pd[off + 1] = a1; pd[off + 2] = a2;
    pi[off + 0] = b0; pi[off + 1] = b1; pi[off + 2] = b2;
  }
}

// ---------------- fused merge + gather + max: one wave per point, 48 partial keys.
// Merge = 3x lexicographic (d2,idx) wave-min; equal-d2 ties resolve to smaller idx =
// reference top_k semantics. Sentinel entries (d2=R2L, idx=0) sort after all real
// candidates and mask to NR, so duplicate-sentinel clearing is harmless.
__global__ __launch_bounds__(256) void k_gather_max(const unsigned short* __restrict__ rgbTb,
                                                    const float* __restrict__ pd,
                                                    const int* __restrict__ pi,
                                                    unsigned short* __restrict__ xcat,
                                                    unsigned short* __restrict__ x2) {
  int t = threadIdx.x, lane = t & 63, w = t >> 6;
  int n = blockIdx.x * 4 + w;
  int g = n >> 8, l = n & 255;
  unsigned long long key = ~0ull;
  if (lane < 48) {
    int s = lane / 3, qq = lane % 3;
    int off = ((g * 16 + s) * 256 + l) * 3 + qq;
    key = ((unsigned long long)__float_as_uint(pd[off]) << 32) | (unsigned int)pi[off];
  }
  unsigned long long mk[3];
#pragma unroll
  for (int r = 0; r < 3; ++r) {
    unsigned long long m = key;
#pragma unroll
    for (int o = 1; o < 64; o <<= 1) {
      unsigned long long other = __shfl_xor(m, o);
      m = other < m ? other : m;
    }
    mk[r] = m;
    if (key == m) key = ~0ull;
  }
  const float R2 = 0.075f * 0.075f;
  float d0 = __uint_as_float((unsigned int)(mk[0] >> 32));
  float d1 = __uint_as_float((unsigned int)(mk[1] >> 32));
  float d2 = __uint_as_float((unsigned int)(mk[2] >> 32));
  int j0 = (d0 > R2) ? NR : (int)(mk[0] & 0xffffffffu);
  int j1 = (d1 > R2) ? NR : (int)(mk[1] & 0xffffffffu);
  int j2 = (d2 > R2) ? NR : (int)(mk[2] & 0xffffffffu);
  unsigned int a = ((const unsigned int*)(rgbTb + (size_t)j0 * 128))[lane];
  unsigned int b = ((const unsigned int*)(rgbTb + (size_t)j1 * 128))[lane];
  unsigned int c = ((const unsigned int*)(rgbTb + (size_t)j2 * 128))[lane];
  unsigned int* xr = (unsigned int*)(xcat + (size_t)n * 384);
  xr[lane] = a; xr[64 + lane] = b; xr[128 + lane] = c;
  float ml = fmaxf(blo(a), fmaxf(blo(b), blo(c)));
  float mh = fmaxf(bhi(a), fmaxf(bhi(b), bhi(c)));
  unsigned int m = (__float_as_uint(mh) & 0xffff0000u) | (__float_as_uint(ml) >> 16);
  ((unsigned int*)(x2 + (size_t)n * 256 + 128))[lane] = m;
}

// ---------------- bf16 MFMA GEMM (unchanged, front chain only)
template <bool BN, bool RELU>
__global__ __launch_bounds__(256) void k_bgemm(const unsigned short* __restrict__ Wb,
                                               const float* __restrict__ bias,
                                               const float* __restrict__ bnp,
                                               const unsigned short* __restrict__ X,
                                               unsigned short* __restrict__ Y,
                                               int O, int C, int ldY) {
  __shared__ unsigned short Xs[128 * 40];
  __shared__ unsigned short Wl[128 * 40];
  __shared__ float scsh[256];
  int t = threadIdx.x;
  int lane = t & 63, w = t >> 6;
  int wn = w & 1, wm = w >> 1;
  int q = lane >> 4, l15 = lane & 15;
  int n0 = blockIdx.x * 128, o0 = blockIdx.y * 128;
  if (t < 128) {
    int o = o0 + t;
    float sc = 0.f, sh = 0.f;
    if (o < O) {
      float b = bias[o];
      if (BN) {
        float g = bnp[o], be = bnp[O + o], m = bnp[2 * O + o], v = bnp[3 * O + o];
        float inv = g * rsqrtf(v + 1e-5f);
        sc = inv; sh = (b - m) * inv + be;
      } else { sc = 1.f; sh = b; }
    }
    scsh[t] = sc; scsh[128 + t] = sh;
  }
  f32x4 acc[4][4] = {};
  for (int c0 = 0; c0 < C; c0 += 32) {
    __syncthreads();
#pragma unroll
    for (int e = 0; e < 2; ++e) {
      int idx = e * 256 + t;
      int row = idx >> 2, kb = idx & 3;
      uint4 xv = *(const uint4*)(X + (size_t)(n0 + row) * C + c0 + kb * 8);
      *(uint4*)&Xs[row * 40 + kb * 8] = xv;
      int go = o0 + row; if (go >= O) go = O - 1;
      uint4 wv = *(const uint4*)(Wb + (size_t)go * C + c0 + kb * 8);
      *(uint4*)&Wl[row * 40 + kb * 8] = wv;
    }
    __syncthreads();
    short8 af[4], bf[4];
#pragma unroll
    for (int a = 0; a < 4; ++a)
      af[a] = *(const short8*)&Wl[(wm * 64 + a * 16 + l15) * 40 + q * 8];
#pragma unroll
    for (int b = 0; b < 4; ++b)
      bf[b] = *(const short8*)&Xs[(wn * 64 + b * 16 + l15) * 40 + q * 8];
#pragma unroll
    for (int a = 0; a < 4; ++a)
#pragma unroll
      for (int b = 0; b < 4; ++b)
        acc[a][b] = __builtin_amdgcn_mfma_f32_16x16x32_bf16(af[a], bf[b], acc[a][b], 0, 0, 0);
  }
  __syncthreads();
  float* lt = (w < 2) ? ((float*)Xs + w * 1280) : ((float*)Wl + (w - 2) * 1280);
#pragma unroll
  for (int a = 0; a < 4; ++a) {
    int oTile = wm * 64 + a * 16;
    if (o0 + oTile >= O) continue;
    float scr[4], shr[4];
#pragma unroll
    for (int r = 0; r < 4; ++r) {
      scr[r] = scsh[oTile + q * 4 + r];
      shr[r] = scsh[128 + oTile + q * 4 + r];
    }
#pragma unroll
    for (int b = 0; b < 4; ++b) {
      int nl = b * 16 + l15;
      f32x4 v;
#pragma unroll
      for (int r = 0; r < 4; ++r) {
        float x = acc[a][b][r] * scr[r] + shr[r];
        if (RELU) x = fmaxf(x, 0.f);
        v[r] = x;
      }
      *(f32x4*)&lt[nl * 20 + q * 4] = v;
    }
#pragma unroll
    for (int g = 0; g < 4; ++g) {
      int nl = g * 16 + (lane >> 2);
      int ob = (lane & 3) * 4;
      f32x4 v = *(const f32x4*)&lt[nl * 20 + ob];
      ushort4 u;
      u.x = f2b(v[0]); u.y = f2b(v[1]); u.z = f2b(v[2]); u.w = f2b(v[3]);
      *(ushort4*)(Y + (size_t)(n0 + wn * 64 + nl) * ldY + o0 + oTile + ob) = u;
    }
  }
}

// ---------------- back-chain layer, o-split across 4 waves (unchanged, R9-verified)
template <int C, int O, bool BN, bool RELU>
__device__ __forceinline__ void back_layer(const unsigned short* __restrict__ W,
                                           const float* __restrict__ bias,
                                           const float* __restrict__ bnp,
                                           const unsigned short* Xs,
                                           unsigned short* Ys,
                                           int w, int q, int l15) {
  constexpr int NT = O / 16;
  constexpr int MT = (NT + 3) / 4;
  f32x4 acc[MT];
#pragma unroll
  for (int i = 0; i < MT; ++i) acc[i] = (f32x4){0.f, 0.f, 0.f, 0.f};
#pragma unroll
  for (int k0 = 0; k0 < C; k0 += 32) {
    short8 bf = *(const short8*)&Xs[l15 * 168 + k0 + q * 8];
#pragma unroll
    for (int i = 0; i < MT; ++i) {
      int ot = w + i * 4;
      if (ot < NT) {
        short8 af = *(const short8*)(W + (size_t)(ot * 16 + l15) * C + k0 + q * 8);
        acc[i] = __builtin_amdgcn_mfma_f32_16x16x32_bf16(af, bf, acc[i], 0, 0, 0);
      }
    }
  }
#pragma unroll
  for (int i = 0; i < MT; ++i) {
    int ot = w + i * 4;
    if (ot >= NT) continue;
    int o4 = ot * 16 + q * 4;
    f32x4 bb = *(const f32x4*)(bias + o4);
    f32x4 sc, sh;
    if (BN) {
      f32x4 g  = *(const f32x4*)(bnp + o4);
      f32x4 be = *(const f32x4*)(bnp + O + o4);
      f32x4 mm = *(const f32x4*)(bnp + 2 * O + o4);
      f32x4 vv = *(const f32x4*)(bnp + 3 * O + o4);
#pragma unroll
      for (int r = 0; r < 4; ++r) {
        float inv = g[r] * rsqrtf(vv[r] + 1e-5f);
        sc[r] = inv; sh[r] = (bb[r] - mm[r]) * inv + be[r];
      }
    } else {
      sc = (f32x4){1.f, 1.f, 1.f, 1.f}; sh = bb;
    }
    ushort4 u;
#pragma unroll
    for (int r = 0; r < 4; ++r) {
      float x = acc[i][r] * sc[r] + sh[r];
      if (RELU) x = fmaxf(x, 0.f);
      ((unsigned short*)&u)[r] = f2b(x);
    }
    *(ushort4*)&Ys[l15 * 168 + ot * 16 + q * 4] = u;
  }
}

// ---------------- fused back chain: 16 rows/block, 1024 blocks (unchanged, R9-verified)
__global__ __launch_bounds__(256) void k_back(const unsigned short* __restrict__ w1,
                                              const unsigned short* __restrict__ w2,
                                              const unsigned short* __restrict__ w3,
                                              const unsigned short* __restrict__ w4,
                                              const float* __restrict__ b1, const float* __restrict__ bn1,
                                              const float* __restrict__ b2, const float* __restrict__ bn2,
                                              const float* __restrict__ b3,
                                              const float* __restrict__ b4, const float* __restrict__ bn4,
                                              const float* __restrict__ wv, const float* __restrict__ bv,
                                              const unsigned short* __restrict__ full,
                                              const float* __restrict__ pxyz,
                                              float* __restrict__ out) {
  __shared__ unsigned short Xb[16 * 168];
  __shared__ unsigned short Yb[16 * 168];
  int t = threadIdx.x, lane = t & 63, w = t >> 6;
  int q = lane >> 4, l15 = lane & 15;
  int n0 = blockIdx.x * 16;
  for (int idx = t; idx < 320; idx += 256) {
    int row = idx / 20, c8 = idx % 20;
    *(uint4*)&Xb[row * 168 + c8 * 8] = *(const uint4*)(full + (size_t)(n0 + row) * 160 + c8 * 8);
  }
  __syncthreads();
  back_layer<160, 160, true,  true >(w1, b1, bn1, Xb, Yb, w, q, l15);
  __syncthreads();
  back_layer<160, 160, true,  true >(w2, b2, bn2, Yb, Xb, w, q, l15);
  __syncthreads();
  back_layer<160, 128, false, false>(w3, b3, nullptr, Xb, Yb, w, q, l15); // fp -> Yb
  __syncthreads();
  back_layer<128, 128, true,  true >(w4, b4, bn4, Yb, Xb, w, q, l15);     // s  -> Xb
  __syncthreads();
  int col8 = (lane & 15) * 8;
  float4 w0 = *(const float4*)(wv + col8);
  float4 wA = *(const float4*)(wv + col8 + 4);
  float bvv = bv[0];
  int row = w * 4 + (lane >> 4);
  uint4 raw = *(const uint4*)&Xb[row * 168 + col8];
  float acc = blo(raw.x) * w0.x + bhi(raw.x) * w0.y + blo(raw.y) * w0.z + bhi(raw.y) * w0.w +
              blo(raw.z) * wA.x + bhi(raw.z) * wA.y + blo(raw.w) * wA.z + bhi(raw.w) * wA.w;
  acc += __shfl_xor(acc, 1); acc += __shfl_xor(acc, 2);
  acc += __shfl_xor(acc, 4); acc += __shfl_xor(acc, 8);
  if ((lane & 15) == 0) out[49152 + n0 + row] = 1.f / (1.f + expf(-(acc + bvv)));
  uint4 rf = *(const uint4*)&Yb[row * 168 + col8];
  float v[8] = {blo(rf.x), bhi(rf.x), blo(rf.y), bhi(rf.y),
                blo(rf.z), bhi(rf.z), blo(rf.w), bhi(rf.w)};
  float s = 0.f;
#pragma unroll
  for (int i = 0; i < 8; ++i) s = fmaf(v[i], v[i], s);
  s += __shfl_xor(s, 1); s += __shfl_xor(s, 2);
  s += __shfl_xor(s, 4); s += __shfl_xor(s, 8);
  float inv = 1.f / fmaxf(sqrtf(s), 1e-12f);
  float* op = out + 65536 + (size_t)(n0 + row) * 128 + col8;
  *(float4*)op = make_float4(v[0] * inv, v[1] * inv, v[2] * inv, v[3] * inv);
  *(float4*)(op + 4) = make_float4(v[4] * inv, v[5] * inv, v[6] * inv, v[7] * inv);
  for (int i = t; i < 48; i += 256) out[n0 * 3 + i] = pxyz[n0 * 3 + i];
}

extern "C" void kernel_launch(void* const* d_in, const int* in_sizes, int n_in,
                              void* d_out, int out_size, void* d_ws, size_t ws_size,
                              hipStream_t stream) {
  const float* pcd_xyz = (const float*)d_in[0];
  const float* rgb_xyz = (const float*)d_in[1];
  const float* pcd_f   = (const float*)d_in[2];
  const float* rgb_f   = (const float*)d_in[3];
  const float* cc1_w = (const float*)d_in[4];  const float* cc1_b = (const float*)d_in[5];
  const float* cc_bn = (const float*)d_in[6];
  const float* cc2_w = (const float*)d_in[7];  const float* cc2_b = (const float*)d_in[8];
  const float* co1_w = (const float*)d_in[9];  const float* co1_b = (const float*)d_in[10];
  const float* co_bn = (const float*)d_in[11];
  const float* co2_w = (const float*)d_in[12]; const float* co2_b = (const float*)d_in[13];
  const float* dh1_w = (const float*)d_in[14]; const float* dh1_b = (const float*)d_in[15];
  const float* dh1_bn = (const float*)d_in[16];
  const float* dh2_w = (const float*)d_in[17]; const float* dh2_b = (const float*)d_in[18];
  const float* dh2_bn = (const float*)d_in[19];
  const float* dh3_w = (const float*)d_in[20]; const float* dh3_b = (const float*)d_in[21];
  const float* sh1_w = (const float*)d_in[22]; const float* sh1_b = (const float*)d_in[23];
  const float* sh_bn = (const float*)d_in[24];
  const float* sh2_w = (const float*)d_in[25]; const float* sh2_b = (const float*)d_in[26];

  char* ws = (char*)d_ws;
  float* out = (float*)d_out;

  unsigned short* wb    = (unsigned short*)(ws);              // 766 KB
  unsigned short* rgbTb = (unsigned short*)(ws + 0x100000);   // 2.1 MB
  float4* rxyz4         = (float4*)(ws + 0x320000);           // 128 KB
  float* pd  = (float*)(ws + 0x400000);                       // 3 MB (16 splits x 3 x NP)
  int*   pi  = (int*)(ws + 0x700000);                         // 3 MB
  unsigned short* xcat = (unsigned short*)(ws + 0xA00000);    // (NP,384)
  unsigned short* h1   = (unsigned short*)(ws + 0x1700000);   // (NP,384)
  unsigned short* x2   = (unsigned short*)(ws + 0x2300000);   // (NP,256)
  unsigned short* h2   = (unsigned short*)(ws + 0x2B00000);   // (NP,256)
  unsigned short* full = (unsigned short*)(ws + 0x3300000);   // (NP,160)

  unsigned short* wb_cc1 = wb;
  unsigned short* wb_cc2 = wb + 147456;
  unsigned short* wb_co1 = wb + 196608;
  unsigned short* wb_co2 = wb + 262144;
  unsigned short* wb_dh1 = wb + 294912;
  unsigned short* wb_dh2 = wb + 320512;
  unsigned short* wb_dh3 = wb + 346112;
  unsigned short* wb_sh1 = wb + 366592;

  k_pre<<<960, 256, 0, stream>>>(rgb_f, rgb_xyz, pcd_f,
                                 cc1_w, cc2_w, co1_w, co2_w, dh1_w, dh2_w, dh3_w, sh1_w,
                                 rgbTb, rxyz4, full, wb);
  k_nn_part<<<dim3(64, 16), 256, 0, stream>>>(pcd_xyz, rxyz4, pd, pi);
  k_gather_max<<<4096, 256, 0, stream>>>(rgbTb, pd, pi, xcat, x2);

  k_bgemm<true, true><<<dim3(128, 3), 256, 0, stream>>>(wb_cc1, cc1_b, cc_bn, xcat, h1, 384, 384, 384);
  k_bgemm<false, false><<<dim3(128, 1), 256, 0, stream>>>(wb_cc2, cc2_b, nullptr, h1, x2, 128, 384, 256);
  k_bgemm<true, true><<<dim3(128, 2), 256, 0, stream>>>(wb_co1, co1_b, co_bn, x2, h2, 256, 256, 256);
  k_bgemm<false, false><<<dim3(128, 1), 256, 0, stream>>>(wb_co2, co2_b, nullptr, h2, full + 32, 128, 256, 160);

  k_back<<<1024, 256, 0, stream>>>(wb_dh1, wb_dh2, wb_dh3, wb_sh1,
                                   dh1_b, dh1_bn, dh2_b, dh2_bn, dh3_b, sh1_b, sh_bn,
                                   sh2_w, sh2_b, full, pcd_xyz, out);
}